// Round 9
// baseline (14656.822 us; speedup 1.0000x reference)
//
#include <hip/hip_runtime.h>
#include <cmath>

// ---------------- numerics model (F-c, validated round 8): ----------------
// f32 tensors, each op computed with f64 internals, one f32 rounding at the
// output. All f64 accumulation orders kept BIT-IDENTICAL to round 8:
//   conv: acc = bias; ic ascending (outer), ky, kx; seq f64 fma
//   conv1 (inside enc12): ky, kx, ic(3) seq f64 fma from b1
//   selu: fl32( selu_f64( c32 ) )
//   S = fl32(f64 seq fma over c);  G_n = fl32(f64 seq fma over c)
//   d_n = (S32 - 2*G32) + E32 (f32);  argmin strict <, first index
// VQ optimization: f32 prefilter m~ = E - 2*Gf (S cancels); exact F-c d
// recomputed only for candidates within margin 4e-7*(S+4).
#define BATCH 32

static const size_t N_H2 = 32u*32*120*120;
static const size_t N_Q  = 32u*64*116*116;
static const size_t RECON_FLOATS = 32u*3*128*128;

static const size_t OFF_W1D  = 0;                         // 2400  f64
static const size_t OFF_W2D  = OFF_W1D + 2400*8;          // 25600 f64
static const size_t OFF_W3D  = OFF_W2D + 25600*8;         // 51200 f64
static const size_t OFF_W4F  = OFF_W3D + 51200*8;         // 51200 f32
static const size_t OFF_W5F  = OFF_W4F + 51200*4;         // 25600 f32
static const size_t OFF_W6F  = OFF_W5F + 25600*4;         // 2400  f32
static const size_t OFF_EMBD = (OFF_W6F + 2400*4 + 255) & ~(size_t)255; // 512*64 f64
static const size_t OFF_EN32 = OFF_EMBD + 32768*8;        // 512 f32
static const size_t OFF_H2F  = (OFF_EN32 + 512*4 + 255) & ~(size_t)255; // 59MB
static const size_t OFF_ZQ   = OFF_H2F + N_H2*4;          // z->q in place, 110MB

__device__ inline double selu64(double r) {
    double neg = 1.6732632423543772848170429916717 * expm1(r);
    return 1.0507009873554804934193349852946 * (r > 0. ? r : neg);
}
__device__ inline float selu32(float r) {
    float neg = 1.6732632423543772848170429916717f * expm1f(r);
    return 1.0507009873554804934193349852946f * (r > 0.f ? r : neg);
}

// ---------------- weight re-layout -> [ky][kx][ic][oc] ----------------
template<typename TOUT>
__global__ void wtrans_k(const float* __restrict__ w, TOUT* __restrict__ wt,
                         int IC, int OC, int trans) {
    int i = blockIdx.x * 256 + threadIdx.x;
    int tot = IC * OC * 25;
    if (i >= tot) return;
    int o  = i % OC;
    int t  = i / OC;
    int ic = t % IC;  t /= IC;
    int kx = t % 5;
    int ky = t / 5;
    float v;
    if (trans) v = w[(((ic * OC) + o) * 5 + ky) * 5 + kx];
    else       v = w[(((o * IC) + ic) * 5 + ky) * 5 + kx];
    wt[i] = (TOUT)v;
}

__global__ void prep_embd(const float* __restrict__ emb, double* __restrict__ embd,
                          float* __restrict__ En32) {
    int n = blockIdx.x * 256 + threadIdx.x;
    if (n >= 512) return;
    double s = 0.;
    for (int c = 0; c < 64; ++c) {
        double e = (double)emb[n * 64 + c];
        embd[n * 64 + c] = e;
        s = fma(e, e, s);
    }
    En32[n] = (float)s;
}

// ------------- fused conv1+conv2, f64 internals / f32 boundaries -----------
// 512 threads: pixel = tid&255 (16x16), oc-group = (tid>>8)*16. Wave-uniform w.
__global__ __launch_bounds__(512)
void enc12_k(const float* __restrict__ x, const double* __restrict__ w1,
             const float* __restrict__ b1, const double* __restrict__ w2,
             const float* __restrict__ b2, float* __restrict__ h2out) {
    __shared__ float xs[3][24][24];
    __shared__ float h1s[32][20][20];
    const int tid = threadIdx.x;
    const int ox0 = blockIdx.x * 16, oy0 = blockIdx.y * 16;
    const int b = blockIdx.z;

    for (int i = tid; i < 3 * 576; i += 512) {
        int ic = i / 576;
        int r  = i - ic * 576;
        int sy = r / 24, sx = r - sy * 24;
        int gy = oy0 + sy, gx = ox0 + sx;
        float v = 0.f;
        if (gy < 128 && gx < 128)
            v = x[((size_t)(b * 3 + ic) * 128 + gy) * 128 + gx];
        xs[ic][sy][sx] = v;
    }
    __syncthreads();

    // h1 tile [32][20][20]: 12800 values, 25/thread; conv1 order: ky,kx,ic(3)
    for (int j = tid; j < 32 * 400; j += 512) {
        int ch = j / 400;
        int r  = j - ch * 400;
        int sy = r / 20, sx = r - sy * 20;
        int gy = oy0 + sy, gx = ox0 + sx;
        float hv = 0.f;
        if (gy < 124 && gx < 124) {
            double a = (double)b1[ch];
#pragma unroll
            for (int ky = 0; ky < 5; ++ky)
#pragma unroll
                for (int kx = 0; kx < 5; ++kx)
#pragma unroll
                    for (int ic = 0; ic < 3; ++ic)
                        a = fma((double)xs[ic][sy + ky][sx + kx],
                                w1[((size_t)(ky * 5 + kx) * 3 + ic) * 32 + ch], a);
            float c32 = (float)a;
            hv = (float)selu64((double)c32);
        }
        h1s[ch][sy][sx] = hv;
    }
    __syncthreads();

    const int px = tid & 15, py = (tid >> 4) & 15;
    const int og = (tid >> 8) * 16;

    double acc[16];
#pragma unroll
    for (int o = 0; o < 16; ++o) acc[o] = (double)b2[og + o];

    for (int ic = 0; ic < 32; ++ic) {
#pragma unroll
        for (int ky = 0; ky < 5; ++ky)
#pragma unroll
            for (int kx = 0; kx < 5; ++kx) {
                double v = (double)h1s[ic][py + ky][px + kx];
                const double* wp = w2 + ((size_t)(ky * 5 + kx) * 32 + ic) * 32 + og;
#pragma unroll
                for (int o = 0; o < 16; ++o)
                    acc[o] = fma(v, wp[o], acc[o]);
            }
    }

    const int y2 = oy0 + py, x2 = ox0 + px;
    if (y2 < 120 && x2 < 120) {
#pragma unroll
        for (int o = 0; o < 16; ++o) {
            float c32 = (float)acc[o];
            h2out[((size_t)(b * 32 + og + o) * 120 + y2) * 120 + x2]
                = (float)selu64((double)c32);
        }
    }
}

// ------------- conv3 (32->64), f64 acc -> f32 z ----------------
// 256 threads: pixel = tid&63 (8x8), oc-group = (tid>>6)*16.
__global__ __launch_bounds__(256)
void conv3_k(const float* __restrict__ h2, const double* __restrict__ wt,
             const float* __restrict__ bias, float* __restrict__ z) {
    __shared__ float h2s[32][12][12];
    const int tid = threadIdx.x;
    const int ox0 = blockIdx.x * 8, oy0 = blockIdx.y * 8;
    const int b = blockIdx.z;

    for (int i = tid; i < 32 * 144; i += 256) {
        int ic = i / 144;
        int r  = i - ic * 144;
        int sy = r / 12, sx = r - sy * 12;
        int gy = oy0 + sy, gx = ox0 + sx;
        float v = 0.f;
        if (gy < 120 && gx < 120)
            v = h2[((size_t)(b * 32 + ic) * 120 + gy) * 120 + gx];
        h2s[ic][sy][sx] = v;
    }
    __syncthreads();

    const int px = tid & 7, py = (tid >> 3) & 7;
    const int og = (tid >> 6) * 16;

    double acc[16];
#pragma unroll
    for (int o = 0; o < 16; ++o) acc[o] = (double)bias[og + o];

    for (int ic = 0; ic < 32; ++ic) {
#pragma unroll
        for (int ky = 0; ky < 5; ++ky)
#pragma unroll
            for (int kx = 0; kx < 5; ++kx) {
                double v = (double)h2s[ic][py + ky][px + kx];
                const double* wp = wt + ((size_t)(ky * 5 + kx) * 32 + ic) * 64 + og;
#pragma unroll
                for (int o = 0; o < 16; ++o)
                    acc[o] = fma(v, wp[o], acc[o]);
            }
    }

    const int oy = oy0 + py, ox = ox0 + px;
    if (oy < 116 && ox < 116) {
#pragma unroll
        for (int o = 0; o < 16; ++o)
            z[((size_t)(b * 64 + og + o) * 116 + oy) * 116 + ox] = (float)acc[o];
    }
}

// ------------- VQ: f32 prefilter + exact F-c f64 recheck ----------------
__global__ __launch_bounds__(256)
void vq2_k(const float* __restrict__ z, float* __restrict__ q,
           const float* __restrict__ embf, const double* __restrict__ embd,
           const float* __restrict__ En32, float* __restrict__ idxo) {
    const int HW = 116 * 116;
    int p = blockIdx.x * 256 + threadIdx.x;
    int b = p / HW;
    int r = p - b * HW;
    const float* zp = z + (size_t)(b * 64) * HW + r;

    float zc[64];
#pragma unroll
    for (int c = 0; c < 64; ++c) zc[c] = zp[(size_t)c * HW];

    double Sd = 0.;
#pragma unroll
    for (int c = 0; c < 64; ++c) {
        double zv = (double)zc[c];
        Sd = fma(zv, zv, Sd);
    }
    const float S32 = (float)Sd;

    // pass 1: f32 prefilter min of m~ = E - 2*Gf  (S cancels in argmin)
    float mmin = __builtin_huge_valf();
    for (int n = 0; n < 512; n += 4) {
        const float* e0 = embf + (size_t)n * 64;
        const float* e1 = e0 + 64;
        const float* e2 = e0 + 128;
        const float* e3 = e0 + 192;
        float G0 = 0.f, G1 = 0.f, G2 = 0.f, G3 = 0.f;
#pragma unroll
        for (int c = 0; c < 64; ++c) {
            float zv = zc[c];
            G0 = fmaf(zv, e0[c], G0);
            G1 = fmaf(zv, e1[c], G1);
            G2 = fmaf(zv, e2[c], G2);
            G3 = fmaf(zv, e3[c], G3);
        }
        float m0 = fmaf(-2.f, G0, En32[n]);
        float m1 = fmaf(-2.f, G1, En32[n + 1]);
        float m2 = fmaf(-2.f, G2, En32[n + 2]);
        float m3 = fmaf(-2.f, G3, En32[n + 3]);
        mmin = fminf(mmin, fminf(fminf(m0, m1), fminf(m2, m3)));
    }
    const float thr = mmin + 4.0e-7f * (S32 + 4.0f);

    // pass 2: exact F-c d for candidates, ascending n, strict <
    float bestd = __builtin_huge_valf();
    int best = 0;
    for (int n = 0; n < 512; n += 4) {
        const float* e0 = embf + (size_t)n * 64;
        const float* e1 = e0 + 64;
        const float* e2 = e0 + 128;
        const float* e3 = e0 + 192;
        float G0 = 0.f, G1 = 0.f, G2 = 0.f, G3 = 0.f;
#pragma unroll
        for (int c = 0; c < 64; ++c) {
            float zv = zc[c];
            G0 = fmaf(zv, e0[c], G0);
            G1 = fmaf(zv, e1[c], G1);
            G2 = fmaf(zv, e2[c], G2);
            G3 = fmaf(zv, e3[c], G3);
        }
        float m[4] = { fmaf(-2.f, G0, En32[n]),     fmaf(-2.f, G1, En32[n + 1]),
                       fmaf(-2.f, G2, En32[n + 2]), fmaf(-2.f, G3, En32[n + 3]) };
#pragma unroll
        for (int j = 0; j < 4; ++j) {
            if (m[j] <= thr) {
                const double* ed = embd + (size_t)(n + j) * 64;
                double Gd = 0.;
#pragma unroll
                for (int c = 0; c < 64; ++c)
                    Gd = fma((double)zc[c], ed[c], Gd);
                float g = (float)Gd;
                float d = (S32 - 2.0f * g) + En32[n + j];
                if (d < bestd) { bestd = d; best = n + j; }
            }
        }
    }

    const float* e = embf + (size_t)best * 64;
    float* qp = q + (size_t)(b * 64) * HW + r;
#pragma unroll
    for (int c = 0; c < 64; ++c) {
        float zv = zc[c];
        float diff = e[c] - zv;
        qp[(size_t)c * HW] = zv + diff;
    }
    idxo[p] = (float)best;
}

// ---------------- decoder (unchanged from round 8, passes) ----------------
template<int IC, int ICB, int OC, bool DOSELU>
__global__ __launch_bounds__(256)
void deconv5_k(const float* __restrict__ in, const float* __restrict__ wt,
               const float* __restrict__ bias, float* __restrict__ out,
               int Hin, int Win, int Hout, int Wout) {
    constexpr int NCH = IC / ICB;
    __shared__ float slds[ICB][20][20];
    const int tid = threadIdx.x;
    const int tx = tid & 15, ty = tid >> 4;
    const int ox0 = blockIdx.x * 16, oy0 = blockIdx.y * 16;
    const int b = blockIdx.z;

    float acc[OC];
#pragma unroll
    for (int o = 0; o < OC; ++o) acc[o] = bias[o];

    for (int cc = 0; cc < NCH; ++cc) {
        __syncthreads();
        for (int i = tid; i < ICB * 400; i += 256) {
            int ic = i / 400;
            int r  = i - ic * 400;
            int sy = r / 20, sx = r - sy * 20;
            int gy = oy0 - 4 + sy;
            int gx = ox0 - 4 + sx;
            float v = 0.f;
            if (gy >= 0 && gy < Hin && gx >= 0 && gx < Win)
                v = in[((size_t)(b * IC + cc * ICB + ic) * Hin + gy) * Win + gx];
            slds[ic][sy][sx] = v;
        }
        __syncthreads();

        for (int ic = 0; ic < ICB; ++ic) {
            int gic = cc * ICB + ic;
#pragma unroll
            for (int ky = 0; ky < 5; ++ky)
#pragma unroll
                for (int kx = 0; kx < 5; ++kx) {
                    float v = slds[ic][ty + ky][tx + kx];
                    const float* wp = wt + ((size_t)(ky * 5 + kx) * IC + gic) * OC;
#pragma unroll
                    for (int o = 0; o < OC; ++o)
                        acc[o] = fmaf(v, wp[o], acc[o]);
                }
        }
    }

    const int oy = oy0 + ty, ox = ox0 + tx;
    if (oy < Hout && ox < Wout) {
#pragma unroll
        for (int o = 0; o < OC; ++o) {
            float r = acc[o];
            if (DOSELU) r = selu32(r);
            out[((size_t)(b * OC + o) * Hout + oy) * Wout + ox] = r;
        }
    }
}

// ---------------- launcher ----------------
extern "C" void kernel_launch(void* const* d_in, const int* in_sizes, int n_in,
                              void* d_out, int out_size, void* d_ws, size_t ws_size,
                              hipStream_t stream) {
    const float* x   = (const float*)d_in[0];
    const float* ew1 = (const float*)d_in[1];
    const float* eb1 = (const float*)d_in[2];
    const float* ew2 = (const float*)d_in[3];
    const float* eb2 = (const float*)d_in[4];
    const float* ew3 = (const float*)d_in[5];
    const float* eb3 = (const float*)d_in[6];
    const float* dw1 = (const float*)d_in[7];
    const float* db1 = (const float*)d_in[8];
    const float* dw2 = (const float*)d_in[9];
    const float* db2 = (const float*)d_in[10];
    const float* dw3 = (const float*)d_in[11];
    const float* db3 = (const float*)d_in[12];
    const float* emb = (const float*)d_in[13];

    char* base = (char*)d_ws;
    double* W1D  = (double*)(base + OFF_W1D);
    double* W2D  = (double*)(base + OFF_W2D);
    double* W3D  = (double*)(base + OFF_W3D);
    float*  W4F  = (float*) (base + OFF_W4F);
    float*  W5F  = (float*) (base + OFF_W5F);
    float*  W6F  = (float*) (base + OFF_W6F);
    double* EMBD = (double*)(base + OFF_EMBD);
    float*  EN32 = (float*) (base + OFF_EN32);
    float*  H2F  = (float*) (base + OFF_H2F);
    float*  ZQ   = (float*) (base + OFF_ZQ);
    float*  D1   = (float*) (base + OFF_H2F);   // h2 dead by then
    float*  D2   = (float*) (base + OFF_ZQ);    // q dead after convT1

    float* recon = (float*)d_out;
    float* idxo  = (float*)d_out + RECON_FLOATS;

    wtrans_k<double><<<dim3((2400  + 255) / 256), 256, 0, stream>>>(ew1, W1D,  3, 32, 0);
    wtrans_k<double><<<dim3((25600 + 255) / 256), 256, 0, stream>>>(ew2, W2D, 32, 32, 0);
    wtrans_k<double><<<dim3((51200 + 255) / 256), 256, 0, stream>>>(ew3, W3D, 32, 64, 0);
    wtrans_k<float ><<<dim3((51200 + 255) / 256), 256, 0, stream>>>(dw1, W4F, 64, 32, 1);
    wtrans_k<float ><<<dim3((25600 + 255) / 256), 256, 0, stream>>>(dw2, W5F, 32, 32, 1);
    wtrans_k<float ><<<dim3((2400  + 255) / 256), 256, 0, stream>>>(dw3, W6F, 32,  3, 1);
    prep_embd<<<dim3(2), 256, 0, stream>>>(emb, EMBD, EN32);

    enc12_k<<<dim3(8, 8, BATCH), 512, 0, stream>>>(x, W1D, eb1, W2D, eb2, H2F);
    conv3_k<<<dim3(15, 15, BATCH), 256, 0, stream>>>(H2F, W3D, eb3, ZQ);
    {
        int P = BATCH * 116 * 116;                  // 430592 = 1682*256 exact
        vq2_k<<<dim3(P / 256), 256, 0, stream>>>(ZQ, ZQ, emb, EMBD, EN32, idxo);
    }

    deconv5_k<64, 32, 32, true ><<<dim3(8, 8, BATCH), 256, 0, stream>>>(ZQ, W4F, db1, D1, 116, 116, 120, 120);
    deconv5_k<32, 32, 32, true ><<<dim3(8, 8, BATCH), 256, 0, stream>>>(D1, W5F, db2, D2, 120, 120, 124, 124);
    deconv5_k<32, 32, 3,  false><<<dim3(8, 8, BATCH), 256, 0, stream>>>(D2, W6F, db3, recon, 124, 124, 128, 128);
}

// Round 10
// 8850.880 us; speedup vs baseline: 1.6560x; 1.6560x over previous
//
#include <hip/hip_runtime.h>
#include <cmath>

// ---------------- numerics model (F-c, validated rounds 8 & 9): ------------
// f32 tensors; every op computed with f64 internals, ONE f32 rounding at the
// op output. f64 accumulation order is free (2^-52 noise vs f32 ulp); the f32
// boundaries are what must be exact:
//   h1 = fl32(selu64(fl32(conv_f64))), h2 same, z = fl32(conv_f64)
//   S = fl32(f64 sum z^2), G = fl32(f64 dot), E = fl32(f64 sum e^2)
//   d = (S32 - 2*G32) + E32 in f32; argmin strict <, first index
// VQ: f32 prefilter (S cancels) + exact F-c recheck within margin (round 9).
#define BATCH 32

static const size_t N_H2 = 32u*32*120*120;
static const size_t RECON_FLOATS = 32u*3*128*128;

static const size_t OFF_W1D  = 0;                         // 2400  f64
static const size_t OFF_W2D  = OFF_W1D + 2400*8;          // 25600 f64
static const size_t OFF_W3D  = OFF_W2D + 25600*8;         // 51200 f64
static const size_t OFF_W4F  = OFF_W3D + 51200*8;         // 51200 f32
static const size_t OFF_W5F  = OFF_W4F + 51200*4;         // 25600 f32
static const size_t OFF_W6F  = OFF_W5F + 25600*4;         // 2400  f32
static const size_t OFF_EMBD = (OFF_W6F + 2400*4 + 255) & ~(size_t)255; // 512*64 f64
static const size_t OFF_EN32 = OFF_EMBD + 32768*8;        // 512 f32
static const size_t OFF_H2F  = (OFF_EN32 + 512*4 + 255) & ~(size_t)255; // 59MB
static const size_t OFF_ZQ   = OFF_H2F + N_H2*4;          // z->q in place, 110MB

__device__ inline double selu64(double r) {
    double neg = 1.6732632423543772848170429916717 * expm1(r);
    return 1.0507009873554804934193349852946 * (r > 0. ? r : neg);
}
__device__ inline float selu32(float r) {
    float neg = 1.6732632423543772848170429916717f * expm1f(r);
    return 1.0507009873554804934193349852946f * (r > 0.f ? r : neg);
}

// ---------------- weight re-layout -> [ky][kx][ic][oc] ----------------
template<typename TOUT>
__global__ void wtrans_k(const float* __restrict__ w, TOUT* __restrict__ wt,
                         int IC, int OC, int trans) {
    int i = blockIdx.x * 256 + threadIdx.x;
    int tot = IC * OC * 25;
    if (i >= tot) return;
    int o  = i % OC;
    int t  = i / OC;
    int ic = t % IC;  t /= IC;
    int kx = t % 5;
    int ky = t / 5;
    float v;
    if (trans) v = w[(((ic * OC) + o) * 5 + ky) * 5 + kx];
    else       v = w[(((o * IC) + ic) * 5 + ky) * 5 + kx];
    wt[i] = (TOUT)v;
}

__global__ void prep_embd(const float* __restrict__ emb, double* __restrict__ embd,
                          float* __restrict__ En32) {
    int n = blockIdx.x * 256 + threadIdx.x;
    if (n >= 512) return;
    double s = 0.;
    for (int c = 0; c < 64; ++c) {
        double e = (double)emb[n * 64 + c];
        embd[n * 64 + c] = e;
        s = fma(e, e, s);
    }
    En32[n] = (float)s;
}

// ---------- fused conv1+conv2, f64 internals / f32 boundaries --------------
// grid (8,8,64): z = b*2 + ocg; block 256 = 16x16 px; 16 oc per thread.
// Weight addresses depend only on blockIdx/loop vars -> scalar s_load path.
__global__ __launch_bounds__(256, 4)
void enc12_k(const float* __restrict__ x, const double* __restrict__ w1,
             const float* __restrict__ b1, const double* __restrict__ w2,
             const float* __restrict__ b2, float* __restrict__ h2out) {
    __shared__ float xs[3][24][24];
    __shared__ float h1s[16][20][20];
    const int tid = threadIdx.x;
    const int px = tid & 15, py = tid >> 4;
    const int ox0 = blockIdx.x * 16, oy0 = blockIdx.y * 16;
    const int b  = blockIdx.z >> 1;
    const int og = (blockIdx.z & 1) * 16;

    for (int i = tid; i < 3 * 576; i += 256) {
        int ic = i / 576;
        int r  = i - ic * 576;
        int sy = r / 24, sx = r - sy * 24;
        int gy = oy0 + sy, gx = ox0 + sx;
        float v = 0.f;
        if (gy < 128 && gx < 128)
            v = x[((size_t)(b * 3 + ic) * 128 + gy) * 128 + gx];
        xs[ic][sy][sx] = v;
    }

    double acc[16];
#pragma unroll
    for (int o = 0; o < 16; ++o) acc[o] = (double)b2[og + o];

    for (int cc = 0; cc < 2; ++cc) {
        __syncthreads();   // xs ready (cc=0) / previous h1s consumed (cc=1)
        // build h1 channels [cc*16, cc*16+16); conv1 order ky,kx,ic(3)
        for (int j = tid; j < 16 * 400; j += 256) {
            int ch = j / 400;
            int r  = j - ch * 400;
            int sy = r / 20, sx = r - sy * 20;
            int oc1 = cc * 16 + ch;
            int gy = oy0 + sy, gx = ox0 + sx;
            float hv = 0.f;
            if (gy < 124 && gx < 124) {
                double a = (double)b1[oc1];
#pragma unroll
                for (int ky = 0; ky < 5; ++ky)
#pragma unroll
                    for (int kx = 0; kx < 5; ++kx)
#pragma unroll
                        for (int ic = 0; ic < 3; ++ic)
                            a = fma((double)xs[ic][sy + ky][sx + kx],
                                    w1[((size_t)(ky * 5 + kx) * 3 + ic) * 32 + oc1], a);
                float c32 = (float)a;               // conv -> f32 boundary
                hv = (float)selu64((double)c32);    // selu -> f32 boundary
            }
            h1s[ch][sy][sx] = hv;
        }
        __syncthreads();

        for (int icl = 0; icl < 16; ++icl) {
            int ic = cc * 16 + icl;                 // ic ascending overall
#pragma unroll
            for (int ky = 0; ky < 5; ++ky)
#pragma unroll
                for (int kx = 0; kx < 5; ++kx) {
                    double v = (double)h1s[icl][py + ky][px + kx];
                    const double* wq = w2 + ((size_t)(ky * 5 + kx) * 32 + ic) * 32 + og;
#pragma unroll
                    for (int o = 0; o < 16; ++o)
                        acc[o] = fma(v, wq[o], acc[o]);
                }
        }
    }

    const int y2 = oy0 + py, x2 = ox0 + px;
    if (y2 < 120 && x2 < 120) {
#pragma unroll
        for (int o = 0; o < 16; ++o) {
            float c32 = (float)acc[o];
            h2out[((size_t)(b * 32 + og + o) * 120 + y2) * 120 + x2]
                = (float)selu64((double)c32);
        }
    }
}

// ---------- conv3 (32->64), f64 acc -> f32 z; scalar weight path -----------
// grid (8,8,128): z = b*4 + ocg; block 256 = 16x16 px; 16 oc per thread.
__global__ __launch_bounds__(256, 4)
void conv3_k(const float* __restrict__ h2, const double* __restrict__ wt,
             const float* __restrict__ bias, float* __restrict__ z) {
    __shared__ float h2s[16][20][20];
    const int tid = threadIdx.x;
    const int px = tid & 15, py = tid >> 4;
    const int ox0 = blockIdx.x * 16, oy0 = blockIdx.y * 16;
    const int b  = blockIdx.z >> 2;
    const int og = (blockIdx.z & 3) * 16;

    double acc[16];
#pragma unroll
    for (int o = 0; o < 16; ++o) acc[o] = (double)bias[og + o];

    for (int cc = 0; cc < 2; ++cc) {
        __syncthreads();
        for (int i = tid; i < 16 * 400; i += 256) {
            int ic = i / 400;
            int r  = i - ic * 400;
            int sy = r / 20, sx = r - sy * 20;
            int gy = oy0 + sy, gx = ox0 + sx;
            float v = 0.f;
            if (gy < 120 && gx < 120)
                v = h2[((size_t)(b * 32 + cc * 16 + ic) * 120 + gy) * 120 + gx];
            h2s[ic][sy][sx] = v;
        }
        __syncthreads();

        for (int icl = 0; icl < 16; ++icl) {
            int ic = cc * 16 + icl;
#pragma unroll
            for (int ky = 0; ky < 5; ++ky)
#pragma unroll
                for (int kx = 0; kx < 5; ++kx) {
                    double v = (double)h2s[icl][py + ky][px + kx];
                    const double* wq = wt + ((size_t)(ky * 5 + kx) * 32 + ic) * 64 + og;
#pragma unroll
                    for (int o = 0; o < 16; ++o)
                        acc[o] = fma(v, wq[o], acc[o]);
                }
        }
    }

    const int oy = oy0 + py, ox = ox0 + px;
    if (oy < 116 && ox < 116) {
#pragma unroll
        for (int o = 0; o < 16; ++o)
            z[((size_t)(b * 64 + og + o) * 116 + oy) * 116 + ox] = (float)acc[o];
    }
}

// ------------- VQ: f32 prefilter + exact F-c f64 recheck (round 9) ---------
__global__ __launch_bounds__(256)
void vq2_k(const float* __restrict__ z, float* __restrict__ q,
           const float* __restrict__ embf, const double* __restrict__ embd,
           const float* __restrict__ En32, float* __restrict__ idxo) {
    const int HW = 116 * 116;
    int p = blockIdx.x * 256 + threadIdx.x;
    int b = p / HW;
    int r = p - b * HW;
    const float* zp = z + (size_t)(b * 64) * HW + r;

    float zc[64];
#pragma unroll
    for (int c = 0; c < 64; ++c) zc[c] = zp[(size_t)c * HW];

    double Sd = 0.;
#pragma unroll
    for (int c = 0; c < 64; ++c) {
        double zv = (double)zc[c];
        Sd = fma(zv, zv, Sd);
    }
    const float S32 = (float)Sd;

    float mmin = __builtin_huge_valf();
    for (int n = 0; n < 512; n += 4) {
        const float* e0 = embf + (size_t)n * 64;
        const float* e1 = e0 + 64;
        const float* e2 = e0 + 128;
        const float* e3 = e0 + 192;
        float G0 = 0.f, G1 = 0.f, G2 = 0.f, G3 = 0.f;
#pragma unroll
        for (int c = 0; c < 64; ++c) {
            float zv = zc[c];
            G0 = fmaf(zv, e0[c], G0);
            G1 = fmaf(zv, e1[c], G1);
            G2 = fmaf(zv, e2[c], G2);
            G3 = fmaf(zv, e3[c], G3);
        }
        float m0 = fmaf(-2.f, G0, En32[n]);
        float m1 = fmaf(-2.f, G1, En32[n + 1]);
        float m2 = fmaf(-2.f, G2, En32[n + 2]);
        float m3 = fmaf(-2.f, G3, En32[n + 3]);
        mmin = fminf(mmin, fminf(fminf(m0, m1), fminf(m2, m3)));
    }
    const float thr = mmin + 4.0e-7f * (S32 + 4.0f);

    float bestd = __builtin_huge_valf();
    int best = 0;
    for (int n = 0; n < 512; n += 4) {
        const float* e0 = embf + (size_t)n * 64;
        const float* e1 = e0 + 64;
        const float* e2 = e0 + 128;
        const float* e3 = e0 + 192;
        float G0 = 0.f, G1 = 0.f, G2 = 0.f, G3 = 0.f;
#pragma unroll
        for (int c = 0; c < 64; ++c) {
            float zv = zc[c];
            G0 = fmaf(zv, e0[c], G0);
            G1 = fmaf(zv, e1[c], G1);
            G2 = fmaf(zv, e2[c], G2);
            G3 = fmaf(zv, e3[c], G3);
        }
        float m[4] = { fmaf(-2.f, G0, En32[n]),     fmaf(-2.f, G1, En32[n + 1]),
                       fmaf(-2.f, G2, En32[n + 2]), fmaf(-2.f, G3, En32[n + 3]) };
#pragma unroll
        for (int j = 0; j < 4; ++j) {
            if (m[j] <= thr) {
                const double* ed = embd + (size_t)(n + j) * 64;
                double Gd = 0.;
#pragma unroll
                for (int c = 0; c < 64; ++c)
                    Gd = fma((double)zc[c], ed[c], Gd);
                float g = (float)Gd;
                float d = (S32 - 2.0f * g) + En32[n + j];
                if (d < bestd) { bestd = d; best = n + j; }
            }
        }
    }

    const float* e = embf + (size_t)best * 64;
    float* qp = q + (size_t)(b * 64) * HW + r;
#pragma unroll
    for (int c = 0; c < 64; ++c) {
        float zv = zc[c];
        float diff = e[c] - zv;
        qp[(size_t)c * HW] = zv + diff;
    }
    idxo[p] = (float)best;
}

// ---------------- decoder (unchanged; scalar weight addresses) -------------
template<int IC, int ICB, int OC, bool DOSELU>
__global__ __launch_bounds__(256)
void deconv5_k(const float* __restrict__ in, const float* __restrict__ wt,
               const float* __restrict__ bias, float* __restrict__ out,
               int Hin, int Win, int Hout, int Wout) {
    constexpr int NCH = IC / ICB;
    __shared__ float slds[ICB][20][20];
    const int tid = threadIdx.x;
    const int tx = tid & 15, ty = tid >> 4;
    const int ox0 = blockIdx.x * 16, oy0 = blockIdx.y * 16;
    const int b = blockIdx.z;

    float acc[OC];
#pragma unroll
    for (int o = 0; o < OC; ++o) acc[o] = bias[o];

    for (int cc = 0; cc < NCH; ++cc) {
        __syncthreads();
        for (int i = tid; i < ICB * 400; i += 256) {
            int ic = i / 400;
            int r  = i - ic * 400;
            int sy = r / 20, sx = r - sy * 20;
            int gy = oy0 - 4 + sy;
            int gx = ox0 - 4 + sx;
            float v = 0.f;
            if (gy >= 0 && gy < Hin && gx >= 0 && gx < Win)
                v = in[((size_t)(b * IC + cc * ICB + ic) * Hin + gy) * Win + gx];
            slds[ic][sy][sx] = v;
        }
        __syncthreads();

        for (int ic = 0; ic < ICB; ++ic) {
            int gic = cc * ICB + ic;
#pragma unroll
            for (int ky = 0; ky < 5; ++ky)
#pragma unroll
                for (int kx = 0; kx < 5; ++kx) {
                    float v = slds[ic][ty + ky][tx + kx];
                    const float* wp = wt + ((size_t)(ky * 5 + kx) * IC + gic) * OC;
#pragma unroll
                    for (int o = 0; o < OC; ++o)
                        acc[o] = fmaf(v, wp[o], acc[o]);
                }
        }
    }

    const int oy = oy0 + ty, ox = ox0 + tx;
    if (oy < Hout && ox < Wout) {
#pragma unroll
        for (int o = 0; o < OC; ++o) {
            float r = acc[o];
            if (DOSELU) r = selu32(r);
            out[((size_t)(b * OC + o) * Hout + oy) * Wout + ox] = r;
        }
    }
}

// ---------------- launcher ----------------
extern "C" void kernel_launch(void* const* d_in, const int* in_sizes, int n_in,
                              void* d_out, int out_size, void* d_ws, size_t ws_size,
                              hipStream_t stream) {
    const float* x   = (const float*)d_in[0];
    const float* ew1 = (const float*)d_in[1];
    const float* eb1 = (const float*)d_in[2];
    const float* ew2 = (const float*)d_in[3];
    const float* eb2 = (const float*)d_in[4];
    const float* ew3 = (const float*)d_in[5];
    const float* eb3 = (const float*)d_in[6];
    const float* dw1 = (const float*)d_in[7];
    const float* db1 = (const float*)d_in[8];
    const float* dw2 = (const float*)d_in[9];
    const float* db2 = (const float*)d_in[10];
    const float* dw3 = (const float*)d_in[11];
    const float* db3 = (const float*)d_in[12];
    const float* emb = (const float*)d_in[13];

    char* base = (char*)d_ws;
    double* W1D  = (double*)(base + OFF_W1D);
    double* W2D  = (double*)(base + OFF_W2D);
    double* W3D  = (double*)(base + OFF_W3D);
    float*  W4F  = (float*) (base + OFF_W4F);
    float*  W5F  = (float*) (base + OFF_W5F);
    float*  W6F  = (float*) (base + OFF_W6F);
    double* EMBD = (double*)(base + OFF_EMBD);
    float*  EN32 = (float*) (base + OFF_EN32);
    float*  H2F  = (float*) (base + OFF_H2F);
    float*  ZQ   = (float*) (base + OFF_ZQ);
    float*  D1   = (float*) (base + OFF_H2F);   // h2 dead by then
    float*  D2   = (float*) (base + OFF_ZQ);    // q dead after convT1

    float* recon = (float*)d_out;
    float* idxo  = (float*)d_out + RECON_FLOATS;

    wtrans_k<double><<<dim3((2400  + 255) / 256), 256, 0, stream>>>(ew1, W1D,  3, 32, 0);
    wtrans_k<double><<<dim3((25600 + 255) / 256), 256, 0, stream>>>(ew2, W2D, 32, 32, 0);
    wtrans_k<double><<<dim3((51200 + 255) / 256), 256, 0, stream>>>(ew3, W3D, 32, 64, 0);
    wtrans_k<float ><<<dim3((51200 + 255) / 256), 256, 0, stream>>>(dw1, W4F, 64, 32, 1);
    wtrans_k<float ><<<dim3((25600 + 255) / 256), 256, 0, stream>>>(dw2, W5F, 32, 32, 1);
    wtrans_k<float ><<<dim3((2400  + 255) / 256), 256, 0, stream>>>(dw3, W6F, 32,  3, 1);
    prep_embd<<<dim3(2), 256, 0, stream>>>(emb, EMBD, EN32);

    enc12_k<<<dim3(8, 8, BATCH * 2), 256, 0, stream>>>(x, W1D, eb1, W2D, eb2, H2F);
    conv3_k<<<dim3(8, 8, BATCH * 4), 256, 0, stream>>>(H2F, W3D, eb3, ZQ);
    {
        int P = BATCH * 116 * 116;                  // 430592 = 1682*256 exact
        vq2_k<<<dim3(P / 256), 256, 0, stream>>>(ZQ, ZQ, emb, EMBD, EN32, idxo);
    }

    deconv5_k<64, 32, 32, true ><<<dim3(8, 8, BATCH), 256, 0, stream>>>(ZQ, W4F, db1, D1, 116, 116, 120, 120);
    deconv5_k<32, 32, 32, true ><<<dim3(8, 8, BATCH), 256, 0, stream>>>(D1, W5F, db2, D2, 120, 120, 124, 124);
    deconv5_k<32, 32, 3,  false><<<dim3(8, 8, BATCH), 256, 0, stream>>>(D2, W6F, db3, recon, 124, 124, 128, 128);
}

// Round 11
// 6215.926 us; speedup vs baseline: 2.3579x; 1.4239x over previous
//
#include <hip/hip_runtime.h>
#include <cmath>

// ---------------- numerics model (F-c, validated rounds 8-10): -------------
// f32 tensors; every op computed with f64 internals, ONE f32 rounding at the
// op output. Per-code VQ arithmetic kept BIT-IDENTICAL to round 10:
//   m_n = fmaf(-2, G_n, E32_n), G_n = seq fmaf over c ascending (f32)
//   thr = mmin + 4e-7*(S32+4), S32 = fl32(f64 seq fma sum z^2)
//   exact d_n = (S32 - 2*fl32(f64 seq fma dot)) + E32_n; argmin strict <,
//   first index (lexicographic (d,n) min); q = z + (e - z) in f32.
#define BATCH 32

static const size_t N_H2 = 32u*32*120*120;
static const size_t RECON_FLOATS = 32u*3*128*128;

static const size_t OFF_W1D  = 0;                         // 2400  f64
static const size_t OFF_W2D  = OFF_W1D + 2400*8;          // 25600 f64
static const size_t OFF_W3D  = OFF_W2D + 25600*8;         // 51200 f64
static const size_t OFF_W4F  = OFF_W3D + 51200*8;         // 51200 f32
static const size_t OFF_W5F  = OFF_W4F + 51200*4;         // 25600 f32
static const size_t OFF_W6F  = OFF_W5F + 25600*4;         // 2400  f32
static const size_t OFF_EN32 = (OFF_W6F + 2400*4 + 255) & ~(size_t)255;  // 512 f32
static const size_t OFF_H2F  = (OFF_EN32 + 512*4 + 255) & ~(size_t)255;  // 59MB
static const size_t OFF_ZQ   = OFF_H2F + N_H2*4;          // z->q in place, 110MB

__device__ inline double selu64(double r) {
    double neg = 1.6732632423543772848170429916717 * expm1(r);
    return 1.0507009873554804934193349852946 * (r > 0. ? r : neg);
}
__device__ inline float selu32(float r) {
    float neg = 1.6732632423543772848170429916717f * expm1f(r);
    return 1.0507009873554804934193349852946f * (r > 0.f ? r : neg);
}

// ---------------- weight re-layout -> [ky][kx][ic][oc] ----------------
template<typename TOUT>
__global__ void wtrans_k(const float* __restrict__ w, TOUT* __restrict__ wt,
                         int IC, int OC, int trans) {
    int i = blockIdx.x * 256 + threadIdx.x;
    int tot = IC * OC * 25;
    if (i >= tot) return;
    int o  = i % OC;
    int t  = i / OC;
    int ic = t % IC;  t /= IC;
    int kx = t % 5;
    int ky = t / 5;
    float v;
    if (trans) v = w[(((ic * OC) + o) * 5 + ky) * 5 + kx];
    else       v = w[(((o * IC) + ic) * 5 + ky) * 5 + kx];
    wt[i] = (TOUT)v;
}

// E_n = fl32( f64 seq fma sum e^2 )  (identical to rounds 8-10)
__global__ void prep_en32(const float* __restrict__ emb, float* __restrict__ En32) {
    int n = blockIdx.x * 256 + threadIdx.x;
    if (n >= 512) return;
    double s = 0.;
    for (int c = 0; c < 64; ++c) {
        double e = (double)emb[n * 64 + c];
        s = fma(e, e, s);
    }
    En32[n] = (float)s;
}

// ---------- fused conv1+conv2 (unchanged from round 10) --------------------
__global__ __launch_bounds__(256, 4)
void enc12_k(const float* __restrict__ x, const double* __restrict__ w1,
             const float* __restrict__ b1, const double* __restrict__ w2,
             const float* __restrict__ b2, float* __restrict__ h2out) {
    __shared__ float xs[3][24][24];
    __shared__ float h1s[16][20][20];
    const int tid = threadIdx.x;
    const int px = tid & 15, py = tid >> 4;
    const int ox0 = blockIdx.x * 16, oy0 = blockIdx.y * 16;
    const int b  = blockIdx.z >> 1;
    const int og = (blockIdx.z & 1) * 16;

    for (int i = tid; i < 3 * 576; i += 256) {
        int ic = i / 576;
        int r  = i - ic * 576;
        int sy = r / 24, sx = r - sy * 24;
        int gy = oy0 + sy, gx = ox0 + sx;
        float v = 0.f;
        if (gy < 128 && gx < 128)
            v = x[((size_t)(b * 3 + ic) * 128 + gy) * 128 + gx];
        xs[ic][sy][sx] = v;
    }

    double acc[16];
#pragma unroll
    for (int o = 0; o < 16; ++o) acc[o] = (double)b2[og + o];

    for (int cc = 0; cc < 2; ++cc) {
        __syncthreads();
        for (int j = tid; j < 16 * 400; j += 256) {
            int ch = j / 400;
            int r  = j - ch * 400;
            int sy = r / 20, sx = r - sy * 20;
            int oc1 = cc * 16 + ch;
            int gy = oy0 + sy, gx = ox0 + sx;
            float hv = 0.f;
            if (gy < 124 && gx < 124) {
                double a = (double)b1[oc1];
#pragma unroll
                for (int ky = 0; ky < 5; ++ky)
#pragma unroll
                    for (int kx = 0; kx < 5; ++kx)
#pragma unroll
                        for (int ic = 0; ic < 3; ++ic)
                            a = fma((double)xs[ic][sy + ky][sx + kx],
                                    w1[((size_t)(ky * 5 + kx) * 3 + ic) * 32 + oc1], a);
                float c32 = (float)a;
                hv = (float)selu64((double)c32);
            }
            h1s[ch][sy][sx] = hv;
        }
        __syncthreads();

        for (int icl = 0; icl < 16; ++icl) {
            int ic = cc * 16 + icl;
#pragma unroll
            for (int ky = 0; ky < 5; ++ky)
#pragma unroll
                for (int kx = 0; kx < 5; ++kx) {
                    double v = (double)h1s[icl][py + ky][px + kx];
                    const double* wq = w2 + ((size_t)(ky * 5 + kx) * 32 + ic) * 32 + og;
#pragma unroll
                    for (int o = 0; o < 16; ++o)
                        acc[o] = fma(v, wq[o], acc[o]);
                }
        }
    }

    const int y2 = oy0 + py, x2 = ox0 + px;
    if (y2 < 120 && x2 < 120) {
#pragma unroll
        for (int o = 0; o < 16; ++o) {
            float c32 = (float)acc[o];
            h2out[((size_t)(b * 32 + og + o) * 120 + y2) * 120 + x2]
                = (float)selu64((double)c32);
        }
    }
}

// ---------- conv3 (unchanged from round 10) --------------------------------
__global__ __launch_bounds__(256, 4)
void conv3_k(const float* __restrict__ h2, const double* __restrict__ wt,
             const float* __restrict__ bias, float* __restrict__ z) {
    __shared__ float h2s[16][20][20];
    const int tid = threadIdx.x;
    const int px = tid & 15, py = tid >> 4;
    const int ox0 = blockIdx.x * 16, oy0 = blockIdx.y * 16;
    const int b  = blockIdx.z >> 2;
    const int og = (blockIdx.z & 3) * 16;

    double acc[16];
#pragma unroll
    for (int o = 0; o < 16; ++o) acc[o] = (double)bias[og + o];

    for (int cc = 0; cc < 2; ++cc) {
        __syncthreads();
        for (int i = tid; i < 16 * 400; i += 256) {
            int ic = i / 400;
            int r  = i - ic * 400;
            int sy = r / 20, sx = r - sy * 20;
            int gy = oy0 + sy, gx = ox0 + sx;
            float v = 0.f;
            if (gy < 120 && gx < 120)
                v = h2[((size_t)(b * 32 + cc * 16 + ic) * 120 + gy) * 120 + gx];
            h2s[ic][sy][sx] = v;
        }
        __syncthreads();

        for (int icl = 0; icl < 16; ++icl) {
            int ic = cc * 16 + icl;
#pragma unroll
            for (int ky = 0; ky < 5; ++ky)
#pragma unroll
                for (int kx = 0; kx < 5; ++kx) {
                    double v = (double)h2s[icl][py + ky][px + kx];
                    const double* wq = wt + ((size_t)(ky * 5 + kx) * 32 + ic) * 64 + og;
#pragma unroll
                    for (int o = 0; o < 16; ++o)
                        acc[o] = fma(v, wq[o], acc[o]);
                }
        }
    }

    const int oy = oy0 + py, ox = ox0 + px;
    if (oy < 116 && ox < 116) {
#pragma unroll
        for (int o = 0; o < 16; ++o)
            z[((size_t)(b * 64 + og + o) * 116 + oy) * 116 + ox] = (float)acc[o];
    }
}

// ---------- VQ v3: lane-per-code, emb in VGPRs, z via LDS broadcast --------
// Block = 512 threads = 512 codes; strip of 128 pixels. HW = 13456 = 106 strips.
#define VQ_STRIP 128
__global__ __launch_bounds__(512)
void vq3_k(const float* __restrict__ z, float* __restrict__ q,
           const float* __restrict__ embf, const float* __restrict__ En32,
           float* __restrict__ idxo) {
    __shared__ float zs[VQ_STRIP][68];              // padded, f4-aligned rows
    __shared__ float wmin[8][VQ_STRIP];
    __shared__ float thr_s[VQ_STRIP];
    __shared__ float S32_s[VQ_STRIP];
    __shared__ unsigned long long dkey[VQ_STRIP];
    __shared__ int bestn_s[VQ_STRIP];

    const int tid  = threadIdx.x;
    const int lane = tid & 63;
    const int w    = tid >> 6;
    const int n    = tid;                 // this thread's code
    const int HW   = 13456;
    const int bb    = blockIdx.x / 106;
    const int strip = blockIdx.x % 106;
    const int r0    = strip * VQ_STRIP;
    const int plen  = (r0 + VQ_STRIP <= HW) ? VQ_STRIP : (HW - r0);

    // stage z strip: zs[p][c]
    for (int i = tid; i < VQ_STRIP * 64; i += 512) {
        int c = i >> 7, p = i & 127;
        float v = 0.f;
        if (p < plen)
            v = z[((size_t)(bb * 64 + c)) * HW + r0 + p];
        zs[p][c] = v;
    }
    if (tid < VQ_STRIP) dkey[tid] = ~0ull;
    __syncthreads();

    // per-lane code data (loaded once, reused across 128 pixels)
    float e_reg[64];
#pragma unroll
    for (int c4 = 0; c4 < 16; ++c4) {
        float4 ev = *(const float4*)&embf[(size_t)n * 64 + c4 * 4];
        e_reg[c4 * 4 + 0] = ev.x;  e_reg[c4 * 4 + 1] = ev.y;
        e_reg[c4 * 4 + 2] = ev.z;  e_reg[c4 * 4 + 3] = ev.w;
    }
    const float E_n = En32[n];

    // S32 + margin per pixel (f64 seq fma, ascending c — identical to r10)
    if (tid < VQ_STRIP) {
        double Sd = 0.;
#pragma unroll
        for (int c = 0; c < 64; ++c) {
            double zv = (double)zs[tid][c];
            Sd = fma(zv, zv, Sd);
        }
        S32_s[tid] = (float)Sd;
    }
    __syncthreads();

    // scan 1: per-pixel min of m over all codes
    for (int p = 0; p < plen; ++p) {
        float G = 0.f;
#pragma unroll
        for (int c = 0; c < 64; c += 4) {
            float4 zv = *(const float4*)&zs[p][c];   // broadcast ds_read_b128
            G = fmaf(zv.x, e_reg[c],     G);
            G = fmaf(zv.y, e_reg[c + 1], G);
            G = fmaf(zv.z, e_reg[c + 2], G);
            G = fmaf(zv.w, e_reg[c + 3], G);
        }
        float m = fmaf(-2.f, G, E_n);
        float mm = m;
#pragma unroll
        for (int s = 1; s < 64; s <<= 1)
            mm = fminf(mm, __shfl_xor(mm, s));
        if (lane == 0) wmin[w][p] = mm;
    }
    __syncthreads();
    if (tid < VQ_STRIP) {
        float mm = wmin[0][tid];
#pragma unroll
        for (int ww = 1; ww < 8; ++ww) mm = fminf(mm, wmin[ww][tid]);
        thr_s[tid] = mm + 4.0e-7f * (S32_s[tid] + 4.0f);
    }
    __syncthreads();

    // scan 2: candidates -> exact F-c recheck -> lexicographic (d, n) atomicMin
    for (int p = 0; p < plen; ++p) {
        float G = 0.f;
#pragma unroll
        for (int c = 0; c < 64; c += 4) {
            float4 zv = *(const float4*)&zs[p][c];
            G = fmaf(zv.x, e_reg[c],     G);
            G = fmaf(zv.y, e_reg[c + 1], G);
            G = fmaf(zv.z, e_reg[c + 2], G);
            G = fmaf(zv.w, e_reg[c + 3], G);
        }
        float m = fmaf(-2.f, G, E_n);
        if (m <= thr_s[p]) {
            double Gd = 0.;
#pragma unroll
            for (int c = 0; c < 64; ++c)
                Gd = fma((double)zs[p][c], (double)e_reg[c], Gd);
            float g = (float)Gd;
            float d = (S32_s[p] - 2.0f * g) + E_n;
            unsigned ub = __float_as_uint(d);
            ub = (ub & 0x80000000u) ? ~ub : (ub | 0x80000000u);   // monotone map
            unsigned long long key =
                ((unsigned long long)ub << 32) | (unsigned)n;
            atomicMin(&dkey[p], key);
        }
    }
    __syncthreads();

    if (tid < plen) {
        int best = (int)(unsigned)(dkey[tid] & 0xffffffffull);
        bestn_s[tid] = best;
        idxo[(size_t)bb * HW + r0 + tid] = (float)best;
    }
    __syncthreads();

    // q = z + (e - z), coalesced over pixels
    for (int i = tid; i < VQ_STRIP * 64; i += 512) {
        int c = i >> 7, p = i & 127;
        if (p < plen) {
            float zv = zs[p][c];
            float e  = embf[(size_t)bestn_s[p] * 64 + c];
            float diff = e - zv;
            q[((size_t)(bb * 64 + c)) * HW + r0 + p] = zv + diff;
        }
    }
}

// ---------------- decoder (unchanged from round 10) ------------------------
template<int IC, int ICB, int OC, bool DOSELU>
__global__ __launch_bounds__(256)
void deconv5_k(const float* __restrict__ in, const float* __restrict__ wt,
               const float* __restrict__ bias, float* __restrict__ out,
               int Hin, int Win, int Hout, int Wout) {
    constexpr int NCH = IC / ICB;
    __shared__ float slds[ICB][20][20];
    const int tid = threadIdx.x;
    const int tx = tid & 15, ty = tid >> 4;
    const int ox0 = blockIdx.x * 16, oy0 = blockIdx.y * 16;
    const int b = blockIdx.z;

    float acc[OC];
#pragma unroll
    for (int o = 0; o < OC; ++o) acc[o] = bias[o];

    for (int cc = 0; cc < NCH; ++cc) {
        __syncthreads();
        for (int i = tid; i < ICB * 400; i += 256) {
            int ic = i / 400;
            int r  = i - ic * 400;
            int sy = r / 20, sx = r - sy * 20;
            int gy = oy0 - 4 + sy;
            int gx = ox0 - 4 + sx;
            float v = 0.f;
            if (gy >= 0 && gy < Hin && gx >= 0 && gx < Win)
                v = in[((size_t)(b * IC + cc * ICB + ic) * Hin + gy) * Win + gx];
            slds[ic][sy][sx] = v;
        }
        __syncthreads();

        for (int ic = 0; ic < ICB; ++ic) {
            int gic = cc * ICB + ic;
#pragma unroll
            for (int ky = 0; ky < 5; ++ky)
#pragma unroll
                for (int kx = 0; kx < 5; ++kx) {
                    float v = slds[ic][ty + ky][tx + kx];
                    const float* wp = wt + ((size_t)(ky * 5 + kx) * IC + gic) * OC;
#pragma unroll
                    for (int o = 0; o < OC; ++o)
                        acc[o] = fmaf(v, wp[o], acc[o]);
                }
        }
    }

    const int oy = oy0 + ty, ox = ox0 + tx;
    if (oy < Hout && ox < Wout) {
#pragma unroll
        for (int o = 0; o < OC; ++o) {
            float r = acc[o];
            if (DOSELU) r = selu32(r);
            out[((size_t)(b * OC + o) * Hout + oy) * Wout + ox] = r;
        }
    }
}

// ---------------- launcher ----------------
extern "C" void kernel_launch(void* const* d_in, const int* in_sizes, int n_in,
                              void* d_out, int out_size, void* d_ws, size_t ws_size,
                              hipStream_t stream) {
    const float* x   = (const float*)d_in[0];
    const float* ew1 = (const float*)d_in[1];
    const float* eb1 = (const float*)d_in[2];
    const float* ew2 = (const float*)d_in[3];
    const float* eb2 = (const float*)d_in[4];
    const float* ew3 = (const float*)d_in[5];
    const float* eb3 = (const float*)d_in[6];
    const float* dw1 = (const float*)d_in[7];
    const float* db1 = (const float*)d_in[8];
    const float* dw2 = (const float*)d_in[9];
    const float* db2 = (const float*)d_in[10];
    const float* dw3 = (const float*)d_in[11];
    const float* db3 = (const float*)d_in[12];
    const float* emb = (const float*)d_in[13];

    char* base = (char*)d_ws;
    double* W1D  = (double*)(base + OFF_W1D);
    double* W2D  = (double*)(base + OFF_W2D);
    double* W3D  = (double*)(base + OFF_W3D);
    float*  W4F  = (float*) (base + OFF_W4F);
    float*  W5F  = (float*) (base + OFF_W5F);
    float*  W6F  = (float*) (base + OFF_W6F);
    float*  EN32 = (float*) (base + OFF_EN32);
    float*  H2F  = (float*) (base + OFF_H2F);
    float*  ZQ   = (float*) (base + OFF_ZQ);
    float*  D1   = (float*) (base + OFF_H2F);   // h2 dead by then
    float*  D2   = (float*) (base + OFF_ZQ);    // q dead after convT1

    float* recon = (float*)d_out;
    float* idxo  = (float*)d_out + RECON_FLOATS;

    wtrans_k<double><<<dim3((2400  + 255) / 256), 256, 0, stream>>>(ew1, W1D,  3, 32, 0);
    wtrans_k<double><<<dim3((25600 + 255) / 256), 256, 0, stream>>>(ew2, W2D, 32, 32, 0);
    wtrans_k<double><<<dim3((51200 + 255) / 256), 256, 0, stream>>>(ew3, W3D, 32, 64, 0);
    wtrans_k<float ><<<dim3((51200 + 255) / 256), 256, 0, stream>>>(dw1, W4F, 64, 32, 1);
    wtrans_k<float ><<<dim3((25600 + 255) / 256), 256, 0, stream>>>(dw2, W5F, 32, 32, 1);
    wtrans_k<float ><<<dim3((2400  + 255) / 256), 256, 0, stream>>>(dw3, W6F, 32,  3, 1);
    prep_en32<<<dim3(2), 256, 0, stream>>>(emb, EN32);

    enc12_k<<<dim3(8, 8, BATCH * 2), 256, 0, stream>>>(x, W1D, eb1, W2D, eb2, H2F);
    conv3_k<<<dim3(8, 8, BATCH * 4), 256, 0, stream>>>(H2F, W3D, eb3, ZQ);
    vq3_k<<<dim3(BATCH * 106), 512, 0, stream>>>(ZQ, ZQ, emb, EN32, idxo);

    deconv5_k<64, 32, 32, true ><<<dim3(8, 8, BATCH), 256, 0, stream>>>(ZQ, W4F, db1, D1, 116, 116, 120, 120);
    deconv5_k<32, 32, 32, true ><<<dim3(8, 8, BATCH), 256, 0, stream>>>(D1, W5F, db2, D2, 120, 120, 124, 124);
    deconv5_k<32, 32, 3,  false><<<dim3(8, 8, BATCH), 256, 0, stream>>>(D2, W6F, db3, recon, 124, 124, 128, 128);
}